// Round 1
// baseline (533.847 us; speedup 1.0000x reference)
//
#include <hip/hip_runtime.h>
#include <hip/hip_fp16.h>

#define TOKENS 4096
#define NN 2048
#define IN_DIM 1024
#define OUT_DIM 1024
#define TSTEPS 3

typedef _Float16 half8 __attribute__((ext_vector_type(8)));
typedef _Float16 half4 __attribute__((ext_vector_type(4)));
typedef float f32x4 __attribute__((ext_vector_type(4)));

__device__ __forceinline__ void gload_lds16(const void* g, void* l) {
    __builtin_amdgcn_global_load_lds(
        (const __attribute__((address_space(1))) unsigned*)g,
        (__attribute__((address_space(3))) unsigned*)l, 16, 0, 0);
}

// C[M,N] = A[M,K] @ B^T  where B is stored [N,K] (row j = column j of the math-B).
// A,B f16; accumulate f32.
// EPI 0: C[o] = v            (f32 out)
// EPI 1: v += bias; oSta = f16(v); oS = f16(tanh(v))   (input projection)
// EPI 2: C[o] = v + bias      (output projection)
template<int EPI>
__global__ __launch_bounds__(256)
void gemm_bt(const _Float16* __restrict__ A, const _Float16* __restrict__ B,
             float* __restrict__ C, const float* __restrict__ bias,
             _Float16* __restrict__ oSta, _Float16* __restrict__ oS,
             int M, int N, int K)
{
    __shared__ _Float16 As[128 * 32];
    __shared__ _Float16 Bs[128 * 32];
    const int tid  = threadIdx.x;
    const int wid  = tid >> 6;
    const int lane = tid & 63;
    const int wr = (wid >> 1) * 64;   // wave row offset in tile
    const int wc = (wid & 1) * 64;    // wave col offset in tile
    const int brow = blockIdx.y * 128;
    const int bcol = blockIdx.x * 128;

    f32x4 acc[4][4];
#pragma unroll
    for (int m = 0; m < 4; ++m)
#pragma unroll
        for (int n = 0; n < 4; ++n) acc[m][n] = (f32x4){0.f, 0.f, 0.f, 0.f};

    // staging geometry: thread t loads 16B; row = t>>2 (64 rows/call), col8 = t&3
    const int ldr = tid >> 2;
    const int ldc = (tid & 3) * 8;
    const int wbase = (wid << 4) * 32;   // wave-uniform LDS base (f16 elems)

    const int kq = (lane >> 4) * 8;      // k sub-block for frags
    const int lr = lane & 15;

    for (int k0 = 0; k0 < K; k0 += 32) {
        __syncthreads();
        gload_lds16(A + (size_t)(brow + ldr) * K + k0 + ldc, As + wbase);
        gload_lds16(A + (size_t)(brow + 64 + ldr) * K + k0 + ldc, As + 64 * 32 + wbase);
        gload_lds16(B + (size_t)(bcol + ldr) * K + k0 + ldc, Bs + wbase);
        gload_lds16(B + (size_t)(bcol + 64 + ldr) * K + k0 + ldc, Bs + 64 * 32 + wbase);
        __syncthreads();

        half8 af[4], bf[4];
#pragma unroll
        for (int m = 0; m < 4; ++m)
            af[m] = *(const half8*)&As[(wr + m * 16 + lr) * 32 + kq];
#pragma unroll
        for (int n = 0; n < 4; ++n)
            bf[n] = *(const half8*)&Bs[(wc + n * 16 + lr) * 32 + kq];
#pragma unroll
        for (int m = 0; m < 4; ++m)
#pragma unroll
            for (int n = 0; n < 4; ++n)
                acc[m][n] = __builtin_amdgcn_mfma_f32_16x16x32_f16(af[m], bf[n], acc[m][n], 0, 0, 0);
    }

    // epilogue: C/D layout col = lane&15, row = (lane>>4)*4 + reg  [m89-verified]
    const int cr = (lane >> 4) * 4;
    const int cc = lane & 15;
#pragma unroll
    for (int m = 0; m < 4; ++m) {
#pragma unroll
        for (int n = 0; n < 4; ++n) {
            const int ccol = bcol + wc + n * 16 + cc;
#pragma unroll
            for (int j = 0; j < 4; ++j) {
                const int crow = brow + wr + m * 16 + cr + j;
                float v = acc[m][n][j];
                const size_t o = (size_t)crow * N + ccol;
                if (EPI == 0) {
                    C[o] = v;
                } else if (EPI == 1) {
                    v += bias[ccol];
                    oSta[o] = (_Float16)v;
                    oS[o] = (_Float16)tanhf(v);
                } else {
                    C[o] = v + bias[ccol];
                }
            }
        }
    }
}

// vectorized f32 -> f16 cast
__global__ void cvt_f16(const float* __restrict__ in, _Float16* __restrict__ out, int n4) {
    int i = blockIdx.x * blockDim.x + threadIdx.x;
    if (i < n4) {
        f32x4 v = *(const f32x4*)&in[(size_t)i * 4];
        half4 h;
        h[0] = (_Float16)v[0]; h[1] = (_Float16)v[1];
        h[2] = (_Float16)v[2]; h[3] = (_Float16)v[3];
        *(half4*)&out[(size_t)i * 4] = h;
    }
}

// effT[j][i] = f16(W[i][j]*Mk[i][j]);  JmT[j][i] = f16(J[i][j]*Mk[i][j])
__global__ void transmul2(const float* __restrict__ W, const float* __restrict__ J,
                          const float* __restrict__ Mk,
                          _Float16* __restrict__ effT, _Float16* __restrict__ JmT) {
    __shared__ float tw[32][33];
    __shared__ float tj[32][33];
    const int bx = blockIdx.x * 32, by = blockIdx.y * 32;
    const int tx = threadIdx.x, ty0 = threadIdx.y;
#pragma unroll
    for (int r = 0; r < 4; ++r) {
        int ty = ty0 + r * 8;
        size_t idx = (size_t)(by + ty) * NN + bx + tx;
        float mv = Mk[idx];
        tw[ty][tx] = W[idx] * mv;
        tj[ty][tx] = J[idx] * mv;
    }
    __syncthreads();
#pragma unroll
    for (int r = 0; r < 4; ++r) {
        int ty = ty0 + r * 8;
        size_t o = (size_t)(bx + ty) * NN + by + tx;
        effT[o] = (_Float16)tw[tx][ty];
        JmT[o]  = (_Float16)tj[tx][ty];
    }
}

__global__ void tsc_kernel(const float* __restrict__ theta, float* __restrict__ Tsc) {
    int i = blockIdx.x * blockDim.x + threadIdx.x;
    if (i < NN) Tsc[i] = fabsf(sinf(2.0f * theta[i])) * 0.1f;
}

// state_new = tanh(signal + lam*(sJ*s) + noise*Tsc); write f16(state_new), f16(tanh(state_new))
__global__ void step_kernel(const float* __restrict__ signal, const float* __restrict__ sJ,
                            const float* __restrict__ noise, const float* __restrict__ Tsc,
                            const float* __restrict__ lamp,
                            _Float16* __restrict__ stateH, _Float16* __restrict__ sH) {
    const int i4 = blockIdx.x * blockDim.x + threadIdx.x;
    const float lam = lamp[0];
    const size_t base = (size_t)i4 * 4;
    f32x4 sg = *(const f32x4*)&signal[base];
    f32x4 dj = *(const f32x4*)&sJ[base];
    f32x4 nz = *(const f32x4*)&noise[base];
    const int col4 = (int)(base & (NN - 1));
    f32x4 tv = *(const f32x4*)&Tsc[col4];
    half4 so = *(const half4*)&sH[base];
    half4 hs, hn;
#pragma unroll
    for (int j = 0; j < 4; ++j) {
        float s = (float)so[j];
        float arg = sg[j] + lam * (dj[j] * s) + nz[j] * tv[j];
        float st = tanhf(arg);
        hs[j] = (_Float16)st;
        hn[j] = (_Float16)tanhf(st);
    }
    *(half4*)&stateH[base] = hs;
    *(half4*)&sH[base] = hn;
}

extern "C" void kernel_launch(void* const* d_in, const int* in_sizes, int n_in,
                              void* d_out, int out_size, void* d_ws, size_t ws_size,
                              hipStream_t stream) {
    const float* x       = (const float*)d_in[0];
    const float* W_in    = (const float*)d_in[1];
    const float* b_in    = (const float*)d_in[2];
    const float* weights = (const float*)d_in[3];
    const float* Jmat    = (const float*)d_in[4];
    const float* theta   = (const float*)d_in[5];
    const float* lam     = (const float*)d_in[6];
    const float* mask    = (const float*)d_in[7];
    const float* noise   = (const float*)d_in[8];
    const float* W_out   = (const float*)d_in[9];
    const float* b_out   = (const float*)d_in[10];
    float* out = (float*)d_out;

    char* w = (char*)d_ws;
    auto alloc = [&](size_t b) { char* p = w; w += (b + 255) & ~(size_t)255; return p; };
    _Float16* xh     = (_Float16*)alloc((size_t)TOKENS * IN_DIM * 2);
    _Float16* WinH   = (_Float16*)alloc((size_t)NN * IN_DIM * 2);
    _Float16* WoutH  = (_Float16*)alloc((size_t)OUT_DIM * NN * 2);
    _Float16* effT   = (_Float16*)alloc((size_t)NN * NN * 2);
    _Float16* JmT    = (_Float16*)alloc((size_t)NN * NN * 2);
    _Float16* stateH = (_Float16*)alloc((size_t)TOKENS * NN * 2);
    _Float16* sH     = (_Float16*)alloc((size_t)TOKENS * NN * 2);
    float* Tsc       = (float*)alloc((size_t)NN * 4);
    float* signal    = (float*)alloc((size_t)TOKENS * NN * 4);
    float* sJ        = (float*)alloc((size_t)TOKENS * NN * 4);

    cvt_f16<<<TOKENS * IN_DIM / 4 / 256, 256, 0, stream>>>(x, xh, TOKENS * IN_DIM / 4);
    cvt_f16<<<NN * IN_DIM / 4 / 256, 256, 0, stream>>>(W_in, WinH, NN * IN_DIM / 4);
    cvt_f16<<<OUT_DIM * NN / 4 / 256, 256, 0, stream>>>(W_out, WoutH, OUT_DIM * NN / 4);
    transmul2<<<dim3(NN / 32, NN / 32), dim3(32, 8), 0, stream>>>(weights, Jmat, mask, effT, JmT);
    tsc_kernel<<<NN / 256, 256, 0, stream>>>(theta, Tsc);

    // state = x @ W_in.T + b_in  (W_in is [NN, IN_DIM] == B^T layout natively)
    gemm_bt<1><<<dim3(NN / 128, TOKENS / 128), 256, 0, stream>>>(
        xh, WinH, nullptr, b_in, stateH, sH, TOKENS, NN, IN_DIM);

    for (int t = 0; t < TSTEPS; ++t) {
        gemm_bt<0><<<dim3(NN / 128, TOKENS / 128), 256, 0, stream>>>(
            stateH, effT, signal, nullptr, nullptr, nullptr, TOKENS, NN, NN);
        gemm_bt<0><<<dim3(NN / 128, TOKENS / 128), 256, 0, stream>>>(
            sH, JmT, sJ, nullptr, nullptr, nullptr, TOKENS, NN, NN);
        step_kernel<<<TOKENS * NN / 4 / 256, 256, 0, stream>>>(
            signal, sJ, noise + (size_t)t * TOKENS * NN, Tsc, lam, stateH, sH);
    }

    // out = state @ W_out.T + b_out  (W_out is [OUT_DIM, NN] == B^T layout natively)
    gemm_bt<2><<<dim3(OUT_DIM / 128, TOKENS / 128), 256, 0, stream>>>(
        stateH, WoutH, out, b_out, nullptr, nullptr, TOKENS, OUT_DIM, NN);
}